// Round 3
// baseline (172.808 us; speedup 1.0000x reference)
//
#include <hip/hip_runtime.h>
#include <stdint.h>

#define BM 64
#define NTHREADS 512
#define NWAVES 8

typedef __attribute__((ext_vector_type(8))) short short8;
typedef __attribute__((ext_vector_type(4))) float f32x4;

__device__ __forceinline__ unsigned short f2bf(float f) {
  union { float f; uint32_t u; } v; v.f = f;
  uint32_t u = v.u;
  uint32_t r = (u + 0x7FFFu + ((u >> 16) & 1u)) >> 16;
  return (unsigned short)r;
}

// H[E,128] = relu(concat(src,dst)[E,256] @ W1[256,128] + b1); out = sigmoid(H @ W2 + b2)
__global__ __launch_bounds__(NTHREADS, 8)
void edge_decoder_kernel(const float* __restrict__ src_emb,
                         const float* __restrict__ dst_emb,
                         const int* __restrict__ eidx,
                         const float* __restrict__ W1,
                         const float* __restrict__ b1,
                         const float* __restrict__ W2,
                         const float* __restrict__ b2,
                         float* __restrict__ out,
                         int E, int ntiles) {
  // A-tile: BM rows x 256 bf16 (512 B/row), XOR-swizzled within 128B windows
  __shared__ char Als[BM * 512];          // 32 KB
  __shared__ float rowpart[NWAVES][BM];   // 2 KB  -> 34 KB total -> 4 blocks/CU, 32 waves/CU

  const int tid  = threadIdx.x;
  const int lane = tid & 63;
  const int w    = tid >> 6;           // wave id 0..7, owns cols [w*16, w*16+16)
  const int l15  = lane & 15;
  const int lk8  = (lane >> 4) * 8;    // k-offset within 32-K block

  // ---- B fragment (W1) -> registers, bf16: 8 k-steps x 1 n-frag = 32 VGPRs ----
  const int col = w * 16 + l15;
  short8 bfrag[8];
#pragma unroll
  for (int s = 0; s < 8; ++s) {
    short8 t;
#pragma unroll
    for (int j = 0; j < 8; ++j) {
      const int k = s * 32 + lk8 + j;
      t[j] = (short)f2bf(W1[k * 128 + col]);
    }
    bfrag[s] = t;
  }
  const float b1v = b1[col];
  const float w2v = W2[col];
  const float b2s = b2[0];

  // staging constants: thread handles chunk q (8 f32 -> 8 bf16) of rows r0+16*i
  const int q  = tid & 31;     // 0..15 src half, 16..31 dst half
  const int r0 = tid >> 5;     // 0..15
  const int qq = q & 15;
  const bool is_src = (q < 16);
  const int swz = (l15 & 7) << 4;

  for (int t = blockIdx.x; t < ntiles; t += gridDim.x) {
    const int t0 = t * BM;

    // ---- stage A tile: gather + f32->bf16 + swizzled ds_write_b128 ----
#pragma unroll
    for (int i = 0; i < 4; ++i) {
      const int row = i * 16 + r0;
      const int e = t0 + row;
      if (e < E) {
        const int node = is_src ? eidx[e] : eidx[E + e];
        const float* base = (is_src ? src_emb : dst_emb) + (size_t)node * 128 + qq * 8;
        const float4 f0 = *(const float4*)base;
        const float4 f1 = *(const float4*)(base + 4);
        short8 hv;
        hv[0] = (short)f2bf(f0.x); hv[1] = (short)f2bf(f0.y);
        hv[2] = (short)f2bf(f0.z); hv[3] = (short)f2bf(f0.w);
        hv[4] = (short)f2bf(f1.x); hv[5] = (short)f2bf(f1.y);
        hv[6] = (short)f2bf(f1.z); hv[7] = (short)f2bf(f1.w);
        const int byteoff = row * 512 + ((q * 16) ^ ((row & 7) << 4));
        *(short8*)(Als + byteoff) = hv;
      }
    }
    __syncthreads();

    // ---- MFMA compute + fused epilogue ----
    for (int m = 0; m < 4; ++m) {
      f32x4 acc = {0.f, 0.f, 0.f, 0.f};
      const int rowb = (m * 16 + l15) * 512;
      const int kb0  = lk8 * 2;
#pragma unroll
      for (int s = 0; s < 8; ++s) {
        const int off = rowb + ((s * 64 + kb0) ^ swz);
        const short8 a = *(const short8*)(Als + off);
        acc = __builtin_amdgcn_mfma_f32_16x16x32_bf16(a, bfrag[s], acc, 0, 0, 0);
      }
      // h = relu(acc + b1); partial = h . W2 over this wave's 16 cols
      float pr[4];
#pragma unroll
      for (int reg = 0; reg < 4; ++reg) {
        float h = acc[reg] + b1v; h = h > 0.f ? h : 0.f;
        pr[reg] = h * w2v;
      }
#pragma unroll
      for (int off = 1; off < 16; off <<= 1) {
#pragma unroll
        for (int reg = 0; reg < 4; ++reg)
          pr[reg] += __shfl_xor(pr[reg], off, 64);
      }
      if (l15 == 0) {
        const int rbase = m * 16 + (lane >> 4) * 4;
#pragma unroll
        for (int reg = 0; reg < 4; ++reg)
          rowpart[w][rbase + reg] = pr[reg];
      }
    }
    __syncthreads();

    // ---- cross-wave reduce + sigmoid + store ----
    if (tid < BM) {
      const int e = t0 + tid;
      if (e < E) {
        float sum = b2s;
#pragma unroll
        for (int ww = 0; ww < NWAVES; ++ww) sum += rowpart[ww][tid];
        out[e] = 1.f / (1.f + __expf(-sum));
      }
    }
    __syncthreads();
  }
}

extern "C" void kernel_launch(void* const* d_in, const int* in_sizes, int n_in,
                              void* d_out, int out_size, void* d_ws, size_t ws_size,
                              hipStream_t stream) {
  const float* src = (const float*)d_in[0];
  const float* dst = (const float*)d_in[1];
  const int*   eix = (const int*)d_in[2];
  const float* W1  = (const float*)d_in[3];
  const float* b1  = (const float*)d_in[4];
  const float* W2  = (const float*)d_in[5];
  const float* b2  = (const float*)d_in[6];
  float* out = (float*)d_out;

  const int E = in_sizes[2] / 2;
  const int ntiles = (E + BM - 1) / BM;
  const int grid = ntiles < 2048 ? ntiles : 2048;
  edge_decoder_kernel<<<grid, NTHREADS, 0, stream>>>(src, dst, eix, W1, b1, W2, b2,
                                                     out, E, ntiles);
}

// Round 4
// 75.895 us; speedup vs baseline: 2.2769x; 2.2769x over previous
//
#include <hip/hip_runtime.h>
#include <stdint.h>

typedef __attribute__((ext_vector_type(8))) short short8;
typedef __attribute__((ext_vector_type(4))) float f32x4;

__device__ __forceinline__ unsigned short f2bf(float f) {
  union { float f; uint32_t u; } v; v.f = f;
  uint32_t u = v.u;
  uint32_t r = (u + 0x7FFFu + ((u >> 16) & 1u)) >> 16;
  return (unsigned short)r;
}
__device__ __forceinline__ float bf2f(unsigned short h) {
  union { uint32_t u; float f; } v; v.u = ((uint32_t)h) << 16; return v.f;
}

// ============================================================================
// Phase 1: U[i] = bf16(src_emb[i] @ W1[:128]); V[j] = bf16(dst_emb[j] @ W1[128:])
// Streaming MFMA GEMM, [Nn,128] @ [128,128], one 64-row tile per block.
// gridDim.y = table (0 -> U from src, 1 -> V from dst).
// ============================================================================
#define NBM 64
__global__ __launch_bounds__(256, 4)
void node_phase_kernel(const float* __restrict__ src_emb,
                       const float* __restrict__ dst_emb,
                       const float* __restrict__ W1,
                       unsigned short* __restrict__ UV,
                       int Nn) {
  __shared__ __align__(16) char Als[NBM * 256];   // 64 rows x 128 bf16, 16 KB

  const int tbl = blockIdx.y;
  const float* emb = tbl ? dst_emb : src_emb;
  const float* Wt  = W1 + (size_t)tbl * 128 * 128;
  unsigned short* out = UV + (size_t)tbl * Nn * 128;

  const int tid  = threadIdx.x;
  const int lane = tid & 63;
  const int w    = tid >> 6;          // wave 0..3 -> cols [w*32, w*32+32)
  const int l15  = lane & 15;
  const int lk8  = (lane >> 4) * 8;

  // B fragments: 4 k-steps x 2 n-frags = 32 VGPRs
  short8 bfrag[4][2];
#pragma unroll
  for (int s = 0; s < 4; ++s) {
#pragma unroll
    for (int nf = 0; nf < 2; ++nf) {
      const int col = w * 32 + nf * 16 + l15;
      short8 t;
#pragma unroll
      for (int j = 0; j < 8; ++j) {
        const int k = s * 32 + lk8 + j;
        t[j] = (short)f2bf(Wt[k * 128 + col]);
      }
      bfrag[s][nf] = t;
    }
  }

  const int t0 = blockIdx.x * NBM;
  // stage: thread handles chunk q (8 f32 -> 8 bf16) of rows r0+16*i
  const int q = tid & 15, r0 = tid >> 4;
#pragma unroll
  for (int i = 0; i < 4; ++i) {
    const int row = i * 16 + r0;
    const int node = t0 + row;
    if (node < Nn) {
      const float* base = emb + (size_t)node * 128 + q * 8;
      const float4 f0 = *(const float4*)base;
      const float4 f1 = *(const float4*)(base + 4);
      short8 hv;
      hv[0] = (short)f2bf(f0.x); hv[1] = (short)f2bf(f0.y);
      hv[2] = (short)f2bf(f0.z); hv[3] = (short)f2bf(f0.w);
      hv[4] = (short)f2bf(f1.x); hv[5] = (short)f2bf(f1.y);
      hv[6] = (short)f2bf(f1.z); hv[7] = (short)f2bf(f1.w);
      const int byteoff = row * 256 + ((q * 16) ^ ((row & 7) << 4));
      *(short8*)(Als + byteoff) = hv;
    }
  }
  __syncthreads();

  const int swz = (l15 & 7) << 4;
#pragma unroll
  for (int m = 0; m < 4; ++m) {
    f32x4 acc0 = {0.f, 0.f, 0.f, 0.f};
    f32x4 acc1 = {0.f, 0.f, 0.f, 0.f};
    const int rowb = (m * 16 + l15) * 256;
    const int kb0  = lk8 * 2;
#pragma unroll
    for (int s = 0; s < 4; ++s) {
      const int off = rowb + ((s * 64 + kb0) ^ swz);
      const short8 a = *(const short8*)(Als + off);
      acc0 = __builtin_amdgcn_mfma_f32_16x16x32_bf16(a, bfrag[s][0], acc0, 0, 0, 0);
      acc1 = __builtin_amdgcn_mfma_f32_16x16x32_bf16(a, bfrag[s][1], acc1, 0, 0, 0);
    }
#pragma unroll
    for (int reg = 0; reg < 4; ++reg) {
      const int orow = t0 + m * 16 + ((lane >> 4) * 4) + reg;
      if (orow < Nn) {
        out[(size_t)orow * 128 + w * 32 + l15]      = f2bf(acc0[reg]);
        out[(size_t)orow * 128 + w * 32 + 16 + l15] = f2bf(acc1[reg]);
      }
    }
  }
}

// ============================================================================
// Phase 2: out[e] = sigmoid( sum_c relu(U[s][c]+V[d][c]+b1[c]) * W2[c] + b2 )
// 16 lanes per edge, 8 bf16 channels per lane, no LDS, no MFMA.
// ============================================================================
__global__ __launch_bounds__(256, 8)
void edge_phase_kernel(const unsigned short* __restrict__ UV,
                       const int* __restrict__ eidx,
                       const float* __restrict__ b1,
                       const float* __restrict__ W2,
                       const float* __restrict__ b2,
                       float* __restrict__ out,
                       int E, int Nn) {
  const int tid = threadIdx.x;
  const int l15 = tid & 15;
  const int sg  = tid >> 4;          // subgroup 0..15 within block

  float b1s[8], w2s[8];
#pragma unroll
  for (int j = 0; j < 8; ++j) {
    b1s[j] = b1[l15 * 8 + j];
    w2s[j] = W2[l15 * 8 + j];
  }
  const float b2s = b2[0];
  const unsigned short* U = UV;
  const unsigned short* V = UV + (size_t)Nn * 128;
  const int stride = gridDim.x * 16;

#pragma unroll 2
  for (int e = blockIdx.x * 16 + sg; e < E; e += stride) {
    const int s = eidx[e];
    const int d = eidx[E + e];
    const short8 u8 = *(const short8*)(U + (size_t)s * 128 + l15 * 8);
    const short8 v8 = *(const short8*)(V + (size_t)d * 128 + l15 * 8);
    float acc = 0.f;
#pragma unroll
    for (int j = 0; j < 8; ++j) {
      float g = bf2f((unsigned short)u8[j]) + bf2f((unsigned short)v8[j]) + b1s[j];
      g = g > 0.f ? g : 0.f;
      acc = fmaf(g, w2s[j], acc);
    }
#pragma unroll
    for (int off = 1; off < 16; off <<= 1)
      acc += __shfl_xor(acc, off, 64);
    if (l15 == 0) out[e] = 1.f / (1.f + __expf(-acc));
  }
}

// ============================================================================
// Fallback (proven R2 kernel): fused gather+MFMA, used if ws_size too small.
// ============================================================================
#define BM 64
__global__ __launch_bounds__(256, 4)
void edge_decoder_fused(const float* __restrict__ src_emb,
                        const float* __restrict__ dst_emb,
                        const int* __restrict__ eidx,
                        const float* __restrict__ W1,
                        const float* __restrict__ b1,
                        const float* __restrict__ W2,
                        const float* __restrict__ b2,
                        float* __restrict__ out,
                        int E, int ntiles) {
  __shared__ __align__(16) char Als[BM * 512];
  __shared__ float rowpart[4][BM];

  const int tid  = threadIdx.x;
  const int lane = tid & 63;
  const int w    = tid >> 6;
  const int l15  = lane & 15;
  const int lk8  = (lane >> 4) * 8;

  short8 bfrag[8][2];
#pragma unroll
  for (int s = 0; s < 8; ++s) {
#pragma unroll
    for (int nf = 0; nf < 2; ++nf) {
      const int col = w * 32 + nf * 16 + l15;
      short8 t;
#pragma unroll
      for (int j = 0; j < 8; ++j) {
        const int k = s * 32 + lk8 + j;
        t[j] = (short)f2bf(W1[k * 128 + col]);
      }
      bfrag[s][nf] = t;
    }
  }
  float b1v[2], w2v[2];
#pragma unroll
  for (int nf = 0; nf < 2; ++nf) {
    const int col = w * 32 + nf * 16 + l15;
    b1v[nf] = b1[col];
    w2v[nf] = W2[col];
  }
  const float b2s = b2[0];

  const int q  = tid & 31;
  const int r0 = tid >> 5;
  const int qq = q & 15;
  const bool is_src = (q < 16);
  const int swz = (l15 & 7) << 4;

  for (int t = blockIdx.x; t < ntiles; t += gridDim.x) {
    const int t0 = t * BM;
#pragma unroll
    for (int i = 0; i < 8; ++i) {
      const int row = i * 8 + r0;
      const int e = t0 + row;
      if (e < E) {
        const int node = is_src ? eidx[e] : eidx[E + e];
        const float* base = (is_src ? src_emb : dst_emb) + (size_t)node * 128 + qq * 8;
        const float4 f0 = *(const float4*)base;
        const float4 f1 = *(const float4*)(base + 4);
        short8 hv;
        hv[0] = (short)f2bf(f0.x); hv[1] = (short)f2bf(f0.y);
        hv[2] = (short)f2bf(f0.z); hv[3] = (short)f2bf(f0.w);
        hv[4] = (short)f2bf(f1.x); hv[5] = (short)f2bf(f1.y);
        hv[6] = (short)f2bf(f1.z); hv[7] = (short)f2bf(f1.w);
        const int byteoff = row * 512 + ((q * 16) ^ ((row & 7) << 4));
        *(short8*)(Als + byteoff) = hv;
      }
    }
    __syncthreads();

    for (int m = 0; m < 4; ++m) {
      f32x4 acc0 = {0.f, 0.f, 0.f, 0.f};
      f32x4 acc1 = {0.f, 0.f, 0.f, 0.f};
      const int rowb = (m * 16 + l15) * 512;
      const int kb0  = lk8 * 2;
#pragma unroll
      for (int s = 0; s < 8; ++s) {
        const int off = rowb + ((s * 64 + kb0) ^ swz);
        const short8 a = *(const short8*)(Als + off);
        acc0 = __builtin_amdgcn_mfma_f32_16x16x32_bf16(a, bfrag[s][0], acc0, 0, 0, 0);
        acc1 = __builtin_amdgcn_mfma_f32_16x16x32_bf16(a, bfrag[s][1], acc1, 0, 0, 0);
      }
      float pr[4];
#pragma unroll
      for (int reg = 0; reg < 4; ++reg) {
        float h0 = acc0[reg] + b1v[0]; h0 = h0 > 0.f ? h0 : 0.f;
        float h1 = acc1[reg] + b1v[1]; h1 = h1 > 0.f ? h1 : 0.f;
        pr[reg] = h0 * w2v[0] + h1 * w2v[1];
      }
#pragma unroll
      for (int off = 1; off < 16; off <<= 1) {
#pragma unroll
        for (int reg = 0; reg < 4; ++reg)
          pr[reg] += __shfl_xor(pr[reg], off, 64);
      }
      if (l15 == 0) {
        const int rbase = m * 16 + (lane >> 4) * 4;
#pragma unroll
        for (int reg = 0; reg < 4; ++reg)
          rowpart[w][rbase + reg] = pr[reg];
      }
    }
    __syncthreads();

    if (tid < BM) {
      const int e = t0 + tid;
      if (e < E) {
        const float sum = rowpart[0][tid] + rowpart[1][tid] +
                          rowpart[2][tid] + rowpart[3][tid] + b2s;
        out[e] = 1.f / (1.f + __expf(-sum));
      }
    }
    __syncthreads();
  }
}

extern "C" void kernel_launch(void* const* d_in, const int* in_sizes, int n_in,
                              void* d_out, int out_size, void* d_ws, size_t ws_size,
                              hipStream_t stream) {
  const float* src = (const float*)d_in[0];
  const float* dst = (const float*)d_in[1];
  const int*   eix = (const int*)d_in[2];
  const float* W1  = (const float*)d_in[3];
  const float* b1  = (const float*)d_in[4];
  const float* W2  = (const float*)d_in[5];
  const float* b2  = (const float*)d_in[6];
  float* out = (float*)d_out;

  const int E  = in_sizes[2] / 2;
  const int Nn = in_sizes[0] / 128;
  const size_t uv_bytes = (size_t)Nn * 128 * 2 * sizeof(unsigned short);

  if (ws_size >= uv_bytes) {
    unsigned short* UV = (unsigned short*)d_ws;
    const int ntiles_n = (Nn + NBM - 1) / NBM;
    node_phase_kernel<<<dim3(ntiles_n, 2), 256, 0, stream>>>(src, dst, W1, UV, Nn);
    const int nblk = ((E + 15) / 16 < 2048) ? (E + 15) / 16 : 2048;
    edge_phase_kernel<<<nblk, 256, 0, stream>>>(UV, eix, b1, W2, b2, out, E, Nn);
  } else {
    const int ntiles = (E + BM - 1) / BM;
    const int grid = ntiles < 2048 ? ntiles : 2048;
    edge_decoder_fused<<<grid, 256, 0, stream>>>(src, dst, eix, W1, b1, W2, b2,
                                                 out, E, ntiles);
  }
}

// Round 5
// 75.681 us; speedup vs baseline: 2.2834x; 1.0028x over previous
//
#include <hip/hip_runtime.h>
#include <stdint.h>

typedef __attribute__((ext_vector_type(8))) short short8;
typedef __attribute__((ext_vector_type(4))) float f32x4;

__device__ __forceinline__ unsigned short f2bf(float f) {
  union { float f; uint32_t u; } v; v.f = f;
  uint32_t u = v.u;
  uint32_t r = (u + 0x7FFFu + ((u >> 16) & 1u)) >> 16;
  return (unsigned short)r;
}
__device__ __forceinline__ float bf2f(unsigned short h) {
  union { uint32_t u; float f; } v; v.u = ((uint32_t)h) << 16; return v.f;
}

// ============================================================================
// Phase 1: U[i] = bf16(src_emb[i] @ W1[:128]); V[j] = bf16(dst_emb[j] @ W1[128:])
// Streaming MFMA GEMM, grid-stride over 64-row tiles; bfrag loaded ONCE/block.
// gridDim.y = table (0 -> U from src, 1 -> V from dst).
// ============================================================================
#define NBM 64
__global__ __launch_bounds__(256, 8)
void node_phase_kernel(const float* __restrict__ src_emb,
                       const float* __restrict__ dst_emb,
                       const float* __restrict__ W1,
                       unsigned short* __restrict__ UV,
                       int Nn, int ntiles) {
  __shared__ __align__(16) char Als[NBM * 256];   // 64 rows x 128 bf16, 16 KB

  const int tbl = blockIdx.y;
  const float* emb = tbl ? dst_emb : src_emb;
  const float* Wt  = W1 + (size_t)tbl * 128 * 128;
  unsigned short* outp = UV + (size_t)tbl * Nn * 128;

  const int tid  = threadIdx.x;
  const int lane = tid & 63;
  const int w    = tid >> 6;          // wave 0..3 -> cols [w*32, w*32+32)
  const int l15  = lane & 15;
  const int lk8  = (lane >> 4) * 8;

  // B fragments: 4 k-steps x 2 n-frags = 32 VGPRs, loaded once per block
  short8 bfrag[4][2];
#pragma unroll
  for (int s = 0; s < 4; ++s) {
#pragma unroll
    for (int nf = 0; nf < 2; ++nf) {
      const int col = w * 32 + nf * 16 + l15;
      short8 t;
#pragma unroll
      for (int j = 0; j < 8; ++j) {
        const int k = s * 32 + lk8 + j;
        t[j] = (short)f2bf(Wt[k * 128 + col]);
      }
      bfrag[s][nf] = t;
    }
  }

  const int q = tid & 15, r0 = tid >> 4;
  const int swz = (l15 & 7) << 4;

  for (int t = blockIdx.x; t < ntiles; t += gridDim.x) {
    const int t0 = t * NBM;

    // stage: thread handles chunk q (8 f32 -> 8 bf16) of rows r0+16*i
#pragma unroll
    for (int i = 0; i < 4; ++i) {
      const int row = i * 16 + r0;
      const int node = t0 + row;
      if (node < Nn) {
        const float* base = emb + (size_t)node * 128 + q * 8;
        const float4 f0 = *(const float4*)base;
        const float4 f1 = *(const float4*)(base + 4);
        short8 hv;
        hv[0] = (short)f2bf(f0.x); hv[1] = (short)f2bf(f0.y);
        hv[2] = (short)f2bf(f0.z); hv[3] = (short)f2bf(f0.w);
        hv[4] = (short)f2bf(f1.x); hv[5] = (short)f2bf(f1.y);
        hv[6] = (short)f2bf(f1.z); hv[7] = (short)f2bf(f1.w);
        const int byteoff = row * 256 + ((q * 16) ^ ((row & 7) << 4));
        *(short8*)(Als + byteoff) = hv;
      }
    }
    __syncthreads();

#pragma unroll
    for (int m = 0; m < 4; ++m) {
      f32x4 acc0 = {0.f, 0.f, 0.f, 0.f};
      f32x4 acc1 = {0.f, 0.f, 0.f, 0.f};
      const int rowb = (m * 16 + l15) * 256;
      const int kb0  = lk8 * 2;
#pragma unroll
      for (int s = 0; s < 4; ++s) {
        const int off = rowb + ((s * 64 + kb0) ^ swz);
        const short8 a = *(const short8*)(Als + off);
        acc0 = __builtin_amdgcn_mfma_f32_16x16x32_bf16(a, bfrag[s][0], acc0, 0, 0, 0);
        acc1 = __builtin_amdgcn_mfma_f32_16x16x32_bf16(a, bfrag[s][1], acc1, 0, 0, 0);
      }
#pragma unroll
      for (int reg = 0; reg < 4; ++reg) {
        const int orow = t0 + m * 16 + ((lane >> 4) * 4) + reg;
        if (orow < Nn) {
          outp[(size_t)orow * 128 + w * 32 + l15]      = f2bf(acc0[reg]);
          outp[(size_t)orow * 128 + w * 32 + 16 + l15] = f2bf(acc1[reg]);
        }
      }
    }
    __syncthreads();
  }
}

// ============================================================================
// Phase 2: out[e] = sigmoid( sum_c relu(U[s][c]+V[d][c]+b1[c]) * W2[c] + b2 )
// 16 lanes per edge, 8 bf16 channels per lane, no LDS, no MFMA.
// ============================================================================
__global__ __launch_bounds__(256, 8)
void edge_phase_kernel(const unsigned short* __restrict__ UV,
                       const int* __restrict__ eidx,
                       const float* __restrict__ b1,
                       const float* __restrict__ W2,
                       const float* __restrict__ b2,
                       float* __restrict__ out,
                       int E, int Nn) {
  const int tid = threadIdx.x;
  const int l15 = tid & 15;
  const int sg  = tid >> 4;          // subgroup 0..15 within block

  float b1s[8], w2s[8];
#pragma unroll
  for (int j = 0; j < 8; ++j) {
    b1s[j] = b1[l15 * 8 + j];
    w2s[j] = W2[l15 * 8 + j];
  }
  const float b2s = b2[0];
  const unsigned short* U = UV;
  const unsigned short* V = UV + (size_t)Nn * 128;
  const int stride = gridDim.x * 16;

#pragma unroll 2
  for (int e = blockIdx.x * 16 + sg; e < E; e += stride) {
    const int s = eidx[e];
    const int d = eidx[E + e];
    const short8 u8 = *(const short8*)(U + (size_t)s * 128 + l15 * 8);
    const short8 v8 = *(const short8*)(V + (size_t)d * 128 + l15 * 8);
    float acc = 0.f;
#pragma unroll
    for (int j = 0; j < 8; ++j) {
      float g = bf2f((unsigned short)u8[j]) + bf2f((unsigned short)v8[j]) + b1s[j];
      g = g > 0.f ? g : 0.f;
      acc = fmaf(g, w2s[j], acc);
    }
#pragma unroll
    for (int off = 1; off < 16; off <<= 1)
      acc += __shfl_xor(acc, off, 64);
    if (l15 == 0) out[e] = 1.f / (1.f + __expf(-acc));
  }
}

// ============================================================================
// Fallback (proven R2 kernel): fused gather+MFMA, used if ws_size too small.
// ============================================================================
#define BM 64
__global__ __launch_bounds__(256, 4)
void edge_decoder_fused(const float* __restrict__ src_emb,
                        const float* __restrict__ dst_emb,
                        const int* __restrict__ eidx,
                        const float* __restrict__ W1,
                        const float* __restrict__ b1,
                        const float* __restrict__ W2,
                        const float* __restrict__ b2,
                        float* __restrict__ out,
                        int E, int ntiles) {
  __shared__ __align__(16) char Als[BM * 512];
  __shared__ float rowpart[4][BM];

  const int tid  = threadIdx.x;
  const int lane = tid & 63;
  const int w    = tid >> 6;
  const int l15  = lane & 15;
  const int lk8  = (lane >> 4) * 8;

  short8 bfrag[8][2];
#pragma unroll
  for (int s = 0; s < 8; ++s) {
#pragma unroll
    for (int nf = 0; nf < 2; ++nf) {
      const int col = w * 32 + nf * 16 + l15;
      short8 t;
#pragma unroll
      for (int j = 0; j < 8; ++j) {
        const int k = s * 32 + lk8 + j;
        t[j] = (short)f2bf(W1[k * 128 + col]);
      }
      bfrag[s][nf] = t;
    }
  }
  float b1v[2], w2v[2];
#pragma unroll
  for (int nf = 0; nf < 2; ++nf) {
    const int col = w * 32 + nf * 16 + l15;
    b1v[nf] = b1[col];
    w2v[nf] = W2[col];
  }
  const float b2s = b2[0];

  const int q  = tid & 31;
  const int r0 = tid >> 5;
  const int qq = q & 15;
  const bool is_src = (q < 16);
  const int swz = (l15 & 7) << 4;

  for (int t = blockIdx.x; t < ntiles; t += gridDim.x) {
    const int t0 = t * BM;
#pragma unroll
    for (int i = 0; i < 8; ++i) {
      const int row = i * 8 + r0;
      const int e = t0 + row;
      if (e < E) {
        const int node = is_src ? eidx[e] : eidx[E + e];
        const float* base = (is_src ? src_emb : dst_emb) + (size_t)node * 128 + qq * 8;
        const float4 f0 = *(const float4*)base;
        const float4 f1 = *(const float4*)(base + 4);
        short8 hv;
        hv[0] = (short)f2bf(f0.x); hv[1] = (short)f2bf(f0.y);
        hv[2] = (short)f2bf(f0.z); hv[3] = (short)f2bf(f0.w);
        hv[4] = (short)f2bf(f1.x); hv[5] = (short)f2bf(f1.y);
        hv[6] = (short)f2bf(f1.z); hv[7] = (short)f2bf(f1.w);
        const int byteoff = row * 512 + ((q * 16) ^ ((row & 7) << 4));
        *(short8*)(Als + byteoff) = hv;
      }
    }
    __syncthreads();

    for (int m = 0; m < 4; ++m) {
      f32x4 acc0 = {0.f, 0.f, 0.f, 0.f};
      f32x4 acc1 = {0.f, 0.f, 0.f, 0.f};
      const int rowb = (m * 16 + l15) * 512;
      const int kb0  = lk8 * 2;
#pragma unroll
      for (int s = 0; s < 8; ++s) {
        const int off = rowb + ((s * 64 + kb0) ^ swz);
        const short8 a = *(const short8*)(Als + off);
        acc0 = __builtin_amdgcn_mfma_f32_16x16x32_bf16(a, bfrag[s][0], acc0, 0, 0, 0);
        acc1 = __builtin_amdgcn_mfma_f32_16x16x32_bf16(a, bfrag[s][1], acc1, 0, 0, 0);
      }
      float pr[4];
#pragma unroll
      for (int reg = 0; reg < 4; ++reg) {
        float h0 = acc0[reg] + b1v[0]; h0 = h0 > 0.f ? h0 : 0.f;
        float h1 = acc1[reg] + b1v[1]; h1 = h1 > 0.f ? h1 : 0.f;
        pr[reg] = h0 * w2v[0] + h1 * w2v[1];
      }
#pragma unroll
      for (int off = 1; off < 16; off <<= 1) {
#pragma unroll
        for (int reg = 0; reg < 4; ++reg)
          pr[reg] += __shfl_xor(pr[reg], off, 64);
      }
      if (l15 == 0) {
        const int rbase = m * 16 + (lane >> 4) * 4;
#pragma unroll
        for (int reg = 0; reg < 4; ++reg)
          rowpart[w][rbase + reg] = pr[reg];
      }
    }
    __syncthreads();

    if (tid < BM) {
      const int e = t0 + tid;
      if (e < E) {
        const float sum = rowpart[0][tid] + rowpart[1][tid] +
                          rowpart[2][tid] + rowpart[3][tid] + b2s;
        out[e] = 1.f / (1.f + __expf(-sum));
      }
    }
    __syncthreads();
  }
}

extern "C" void kernel_launch(void* const* d_in, const int* in_sizes, int n_in,
                              void* d_out, int out_size, void* d_ws, size_t ws_size,
                              hipStream_t stream) {
  const float* src = (const float*)d_in[0];
  const float* dst = (const float*)d_in[1];
  const int*   eix = (const int*)d_in[2];
  const float* W1  = (const float*)d_in[3];
  const float* b1  = (const float*)d_in[4];
  const float* W2  = (const float*)d_in[5];
  const float* b2  = (const float*)d_in[6];
  float* out = (float*)d_out;

  const int E  = in_sizes[2] / 2;
  const int Nn = in_sizes[0] / 128;
  const size_t uv_bytes = (size_t)Nn * 128 * 2 * sizeof(unsigned short);

  if (ws_size >= uv_bytes) {
    unsigned short* UV = (unsigned short*)d_ws;
    const int ntiles_n = (Nn + NBM - 1) / NBM;
    const int gx = ntiles_n < 512 ? ntiles_n : 512;
    node_phase_kernel<<<dim3(gx, 2), 256, 0, stream>>>(src, dst, W1, UV, Nn, ntiles_n);
    const int nblk = ((E + 15) / 16 < 2048) ? (E + 15) / 16 : 2048;
    edge_phase_kernel<<<nblk, 256, 0, stream>>>(UV, eix, b1, W2, b2, out, E, Nn);
  } else {
    const int ntiles = (E + BM - 1) / BM;
    const int grid = ntiles < 2048 ? ntiles : 2048;
    edge_decoder_fused<<<grid, 256, 0, stream>>>(src, dst, eix, W1, b1, W2, b2,
                                                 out, E, ntiles);
  }
}